// Round 1
// baseline (570.765 us; speedup 1.0000x reference)
//
#include <hip/hip_runtime.h>
#include <hip/hip_bf16.h>

// Problem constants (from reference): B=8, T=4096, Bc=128, H=512, DILATION=4
#define NB 8
#define NT 4096
#define NC 128
#define NH 512
#define TB 32            // time rows (outputs) per block
#define XR (TB + 8)      // staged rows: halo of 4 on each side (dilation 4, 3 taps)

// Fully fused: GEMM1 + PReLU1 + depthwise dilated conv + PReLU2 + GEMM2 (+x) + GEMM3.
// h never materializes (lives in per-thread registers); y tile staged in LDS f32.
__global__ __launch_bounds__(256) void conv1d_block_fused(
    const float* __restrict__ x,      // (8,4096,128)
    const float* __restrict__ wb,     // (128,512)
    const float* __restrict__ a1,     // (4096,512)
    const float* __restrict__ wd,     // (3,1,512)
    const float* __restrict__ a2,     // (4096,512)
    const float* __restrict__ wres,   // (512,128)
    const float* __restrict__ wskip,  // (512,128)
    float* __restrict__ out)          // residual (8,4096,128) then skip (8,4096,128)
{
    __shared__ float xs[XR][NC];      // 20 KB
    __shared__ float ys[TB][NH];      // 64 KB

    const int tid  = threadIdx.x;
    const int b    = blockIdx.x >> 7;          // 128 tiles per batch (4096/32)
    const int t0   = (blockIdx.x & 127) * TB;

    // ---- Phase 0: stage x rows [t0-4, t0+TB+3], zero-filled out of range ----
    // 40*128 floats = 1280 float4; 256 threads -> 5 each. Coalesced.
    #pragma unroll
    for (int k = 0; k < (XR * NC / 4) / 256; ++k) {
        int f  = tid + k * 256;       // float4 index
        int r  = f >> 5;              // 32 float4 per row
        int c4 = f & 31;
        int t  = t0 - 4 + r;
        float4 v = make_float4(0.f, 0.f, 0.f, 0.f);
        if (t >= 0 && t < NT)
            v = *reinterpret_cast<const float4*>(&x[((size_t)b * NT + t) * NC + c4 * 4]);
        *reinterpret_cast<float4*>(&xs[r][c4 * 4]) = v;
    }
    __syncthreads();

    // ---- Phase 1: h = prelu(x @ wb, a1) in registers; depthwise conv + prelu2 -> ys ----
    for (int pass = 0; pass < 2; ++pass) {
        const int j = tid + pass * 256;        // h-column owned by this thread

        float acc[XR];
        #pragma unroll
        for (int r = 0; r < XR; ++r) acc[r] = 0.f;

        for (int c4 = 0; c4 < NC / 4; ++c4) {
            // w_bottleneck column j, 4 consecutive c (coalesced across threads)
            float w0 = wb[(c4 * 4 + 0) * NH + j];
            float w1 = wb[(c4 * 4 + 1) * NH + j];
            float w2 = wb[(c4 * 4 + 2) * NH + j];
            float w3 = wb[(c4 * 4 + 3) * NH + j];
            #pragma unroll
            for (int r = 0; r < XR; ++r) {
                float4 xv = *reinterpret_cast<const float4*>(&xs[r][c4 * 4]); // broadcast
                acc[r] = fmaf(xv.x, w0, acc[r]);
                acc[r] = fmaf(xv.y, w1, acc[r]);
                acc[r] = fmaf(xv.z, w2, acc[r]);
                acc[r] = fmaf(xv.w, w3, acc[r]);
            }
        }

        // PReLU1 (rows with t outside [0,T) are zero-padding rows of h)
        #pragma unroll
        for (int r = 0; r < XR; ++r) {
            int t = t0 - 4 + r;
            if (t >= 0 && t < NT) {
                float al = a1[(size_t)t * NH + j];
                float v  = acc[r];
                acc[r] = fmaxf(v, 0.f) + al * fminf(v, 0.f);
            } else {
                acc[r] = 0.f;
            }
        }

        // Depthwise dilated conv (taps at t-4, t, t+4) + PReLU2, write y to LDS
        const float k0 = wd[0 * NH + j];
        const float k1 = wd[1 * NH + j];
        const float k2 = wd[2 * NH + j];
        #pragma unroll
        for (int r = 0; r < TB; ++r) {
            float v  = fmaf(k0, acc[r], fmaf(k1, acc[r + 4], k2 * acc[r + 8]));
            float al = a2[(size_t)(t0 + r) * NH + j];
            ys[r][j] = fmaxf(v, 0.f) + al * fminf(v, 0.f);
        }
    }
    __syncthreads();

    // ---- Phase 2: residual = y @ wres + x (waves 0-1); skip = y @ wskip (waves 2-3) ----
    {
        const int  c       = tid & 127;
        const bool is_skip = tid >= 128;       // wave-uniform split (waves 2,3)
        const float* __restrict__ W = is_skip ? wskip : wres;

        float acc[TB];
        #pragma unroll
        for (int r = 0; r < TB; ++r) acc[r] = 0.f;

        for (int j4 = 0; j4 < NH / 4; ++j4) {
            float w0 = W[(j4 * 4 + 0) * NC + c];
            float w1 = W[(j4 * 4 + 1) * NC + c];
            float w2 = W[(j4 * 4 + 2) * NC + c];
            float w3 = W[(j4 * 4 + 3) * NC + c];
            #pragma unroll
            for (int r = 0; r < TB; ++r) {
                float4 yv = *reinterpret_cast<const float4*>(&ys[r][j4 * 4]); // broadcast
                acc[r] = fmaf(yv.x, w0, acc[r]);
                acc[r] = fmaf(yv.y, w1, acc[r]);
                acc[r] = fmaf(yv.z, w2, acc[r]);
                acc[r] = fmaf(yv.w, w3, acc[r]);
            }
        }

        const size_t obase = ((size_t)b * NT + t0) * NC + c;
        #pragma unroll
        for (int r = 0; r < TB; ++r) {
            size_t oi = obase + (size_t)r * NC;
            if (is_skip) out[(size_t)NB * NT * NC + oi] = acc[r];
            else         out[oi] = acc[r] + xs[r + 4][c];   // +x from staged tile
        }
    }
}

extern "C" void kernel_launch(void* const* d_in, const int* in_sizes, int n_in,
                              void* d_out, int out_size, void* d_ws, size_t ws_size,
                              hipStream_t stream) {
    const float* x  = (const float*)d_in[0];
    const float* wb = (const float*)d_in[1];
    const float* a1 = (const float*)d_in[2];
    const float* wd = (const float*)d_in[3];
    const float* a2 = (const float*)d_in[4];
    const float* wr = (const float*)d_in[5];
    const float* wk = (const float*)d_in[6];
    float* out = (float*)d_out;

    dim3 grid(NB * (NT / TB));   // 8 * 128 = 1024 blocks
    dim3 block(256);
    conv1d_block_fused<<<grid, block, 0, stream>>>(x, wb, a1, wd, a2, wr, wk, out);
}

// Round 2
// 70.746 us; speedup vs baseline: 8.0679x; 8.0679x over previous
//
#include <hip/hip_runtime.h>
#include <hip/hip_bf16.h>

#define NB 8
#define NT 4096
#define NC 128
#define NH 512
#define TB 32            // output time rows per block
#define HR 48            // staged h rows: [t0-4, t0+44); conv needs [t0-4, t0+36)

typedef __attribute__((ext_vector_type(8))) short bf16x8;
typedef __attribute__((ext_vector_type(4))) float f32x4;

__device__ __forceinline__ ushort f2bf(float f) {
    uint u = __float_as_uint(f);
    uint r = u + 0x7FFFu + ((u >> 16) & 1u);   // RNE
    return (ushort)(r >> 16);
}

// ---- Prep: convert weights to bf16, pre-swizzled into MFMA B-fragment order ----
// wbt[((kt*32 + jt)*64 + l)*8 + i] = wb[(kt*32 + (l>>4)*8 + i)*512 + jt*16 + (l&15)]
//   kt in [0,4) (K=128), jt in [0,32) (N=512)                      -> 65536 elems
// wct[((kt*16 + jt)*64 + l)*8 + i] = wcat[(kt*32 + (l>>4)*8 + i)*256col j]
//   wcat = [wres | wskip], kt in [0,16) (K=512), jt in [0,16)      -> 131072 elems
__global__ __launch_bounds__(256) void prep_weights(
    const float* __restrict__ wb, const float* __restrict__ wres,
    const float* __restrict__ wskip, short* __restrict__ wbt, short* __restrict__ wct)
{
    int i = blockIdx.x * 256 + threadIdx.x;
    if (i < 65536) {
        int ii = i & 7, l = (i >> 3) & 63, jt = (i >> 9) & 31, kt = i >> 14;
        int k = kt * 32 + (l >> 4) * 8 + ii;
        int j = jt * 16 + (l & 15);
        wbt[i] = (short)f2bf(wb[k * NH + j]);
    } else if (i < 65536 + 131072) {
        int i2 = i - 65536;
        int ii = i2 & 7, l = (i2 >> 3) & 63, jt = (i2 >> 9) & 15, kt = i2 >> 13;
        int k = kt * 32 + (l >> 4) * 8 + ii;
        int j = jt * 16 + (l & 15);
        float v = (j < 128) ? wres[k * NC + j] : wskip[k * NC + (j - 128)];
        wct[i2] = (short)f2bf(v);
    }
}

// ---- Fused main kernel ----
__global__ __launch_bounds__(256, 2) void conv1d_block_mfma(
    const float* __restrict__ x,      // (8,4096,128)
    const float* __restrict__ a1,     // (4096,512)
    const float* __restrict__ wd,     // (3,1,512)
    const float* __restrict__ a2,     // (4096,512)
    const short* __restrict__ wbt,    // prepped wb  (bf16 bits)
    const short* __restrict__ wct,    // prepped [wres|wskip]
    float* __restrict__ out)
{
    // A-fragment layouts: frag (mt,kt): lane l elem i = M[mt*16 + (l&15)][kt*32 + (l>>4)*8 + i]
    __shared__ short xs[3 * 4 * 64 * 8];    // 48x128 x-tile, bf16, 12 KB
    __shared__ short ys[2 * 16 * 64 * 8];   // 32x512 y-tile, bf16, 32 KB

    const int tid  = threadIdx.x;
    const int lane = tid & 63;
    const int wave = tid >> 6;
    const int b    = blockIdx.x >> 7;
    const int t0   = (blockIdx.x & 127) * TB;
    const int jl   = lane & 15;
    const int rb   = (lane >> 4) * 4;       // fragment row base (C/D layout)

    // ---- stage x tile (rows t0-4 .. t0+43, zero outside [0,T)) as bf16 A-frags ----
    #pragma unroll
    for (int it = 0; it < 3; ++it) {
        int chunk = tid + it * 256;          // [0, 768): mt*256 + kt*64 + l
        int mt  = chunk >> 8;
        int kt  = (chunk >> 6) & 3;
        int l   = chunk & 63;
        int row = mt * 16 + (l & 15);
        int t   = t0 - 4 + row;
        int c0  = kt * 32 + (l >> 4) * 8;
        float4 p0 = make_float4(0.f, 0.f, 0.f, 0.f), p1 = p0;
        if (t >= 0 && t < NT) {
            const float* src = &x[((size_t)b * NT + t) * NC + c0];
            p0 = *reinterpret_cast<const float4*>(src);
            p1 = *reinterpret_cast<const float4*>(src + 4);
        }
        bf16x8 s;
        s[0] = (short)f2bf(p0.x); s[1] = (short)f2bf(p0.y);
        s[2] = (short)f2bf(p0.z); s[3] = (short)f2bf(p0.w);
        s[4] = (short)f2bf(p1.x); s[5] = (short)f2bf(p1.y);
        s[6] = (short)f2bf(p1.z); s[7] = (short)f2bf(p1.w);
        *reinterpret_cast<bf16x8*>(&xs[chunk * 8]) = s;
    }
    __syncthreads();

    // ---- GEMM1: h(48x512) = x(48x128) @ wb(128x512); wave owns 128 cols ----
    f32x4 acc1[3][8];
    #pragma unroll
    for (int m = 0; m < 3; ++m)
        #pragma unroll
        for (int n = 0; n < 8; ++n)
            acc1[m][n] = (f32x4){0.f, 0.f, 0.f, 0.f};

    #pragma unroll
    for (int kt = 0; kt < 4; ++kt) {
        bf16x8 af[3];
        #pragma unroll
        for (int m = 0; m < 3; ++m)
            af[m] = *reinterpret_cast<const bf16x8*>(&xs[((m * 4 + kt) * 64 + lane) * 8]);
        #pragma unroll
        for (int n = 0; n < 8; ++n) {
            int jt = wave * 8 + n;
            bf16x8 bfr = *reinterpret_cast<const bf16x8*>(&wbt[((kt * 32 + jt) * 64 + lane) * 8]);
            #pragma unroll
            for (int m = 0; m < 3; ++m)
                acc1[m][n] = __builtin_amdgcn_mfma_f32_16x16x32_bf16(af[m], bfr, acc1[m][n], 0, 0, 0);
        }
    }

    // ---- PReLU1 in-register (rows with t outside [0,T) are exactly 0 already) ----
    #pragma unroll
    for (int m = 0; m < 3; ++m) {
        #pragma unroll
        for (int n = 0; n < 8; ++n) {
            int j = wave * 128 + n * 16 + jl;
            #pragma unroll
            for (int reg = 0; reg < 4; ++reg) {
                int g = m * 16 + rb + reg;
                int t = t0 - 4 + g;
                int tc = min(max(t, 0), NT - 1);          // clamp (value irrelevant when h==0)
                float al = a1[(size_t)tc * NH + j];
                float v  = acc1[m][n][reg];
                acc1[m][n][reg] = fmaxf(v, 0.f) + al * fminf(v, 0.f);
            }
        }
    }

    // ---- depthwise dilated conv (taps g, g+4, g+8) + PReLU2, in-register via shfl ----
    float kw[3][8];
    #pragma unroll
    for (int n = 0; n < 8; ++n) {
        int j = wave * 128 + n * 16 + jl;
        kw[0][n] = wd[0 * NH + j];
        kw[1][n] = wd[1 * NH + j];
        kw[2][n] = wd[2 * NH + j];
    }

    #pragma unroll
    for (int m = 0; m < 2; ++m) {
        #pragma unroll
        for (int n = 0; n < 8; ++n) {
            int j   = wave * 128 + n * 16 + jl;
            int kt2 = j >> 5;
            int l2h = ((j >> 3) & 3) << 4;
            int i2  = j & 7;
            #pragma unroll
            for (int reg = 0; reg < 4; ++reg) {
                float hc = acc1[m][n][reg];
                // h[g+4]: 16 lanes down, crossing into m+1 fragment for lane>=48
                float s1 = __shfl(acc1[m][n][reg],     (lane + 16) & 63);
                float s2 = __shfl(acc1[m + 1][n][reg], (lane + 16) & 63);
                float h4 = (lane < 48) ? s1 : s2;
                // h[g+8]: 32 lanes down, crossing for lane>=32
                float s3 = __shfl(acc1[m][n][reg],     (lane + 32) & 63);
                float s4 = __shfl(acc1[m + 1][n][reg], (lane + 32) & 63);
                float h8 = (lane < 32) ? s3 : s4;
                float v = kw[0][n] * hc + kw[1][n] * h4 + kw[2][n] * h8;
                int g = m * 16 + rb + reg;                 // output row [0,32)
                float al = a2[(size_t)(t0 + g) * NH + j];
                v = fmaxf(v, 0.f) + al * fminf(v, 0.f);
                int l2 = (g & 15) | l2h;
                ys[((m * 16 + kt2) * 64 + l2) * 8 + i2] = (short)f2bf(v);
            }
        }
    }
    __syncthreads();

    // ---- GEMM2/3: out(32x256) = y(32x512) @ [wres|wskip]; wave owns 64 cols ----
    f32x4 acc2[2][4];
    #pragma unroll
    for (int m = 0; m < 2; ++m)
        #pragma unroll
        for (int n = 0; n < 4; ++n)
            acc2[m][n] = (f32x4){0.f, 0.f, 0.f, 0.f};

    #pragma unroll
    for (int kt = 0; kt < 16; ++kt) {
        bf16x8 A0 = *reinterpret_cast<const bf16x8*>(&ys[((0 * 16 + kt) * 64 + lane) * 8]);
        bf16x8 A1 = *reinterpret_cast<const bf16x8*>(&ys[((1 * 16 + kt) * 64 + lane) * 8]);
        #pragma unroll
        for (int n = 0; n < 4; ++n) {
            int jt = wave * 4 + n;
            bf16x8 Bf = *reinterpret_cast<const bf16x8*>(&wct[((kt * 16 + jt) * 64 + lane) * 8]);
            acc2[0][n] = __builtin_amdgcn_mfma_f32_16x16x32_bf16(A0, Bf, acc2[0][n], 0, 0, 0);
            acc2[1][n] = __builtin_amdgcn_mfma_f32_16x16x32_bf16(A1, Bf, acc2[1][n], 0, 0, 0);
        }
    }

    // ---- epilogue: waves 0-1 -> residual (+x), waves 2-3 -> skip ----
    #pragma unroll
    for (int m = 0; m < 2; ++m) {
        #pragma unroll
        for (int n = 0; n < 4; ++n) {
            int j = wave * 64 + n * 16 + jl;              // [0,256), wave-uniform split
            #pragma unroll
            for (int reg = 0; reg < 4; ++reg) {
                int g = m * 16 + rb + reg;
                size_t t = (size_t)(t0 + g);
                float v = acc2[m][n][reg];
                if (j < 128) {
                    size_t idx = ((size_t)b * NT + t) * NC + j;
                    out[idx] = v + x[idx];
                } else {
                    size_t idx = ((size_t)b * NT + t) * NC + (j - 128);
                    out[(size_t)NB * NT * NC + idx] = v;
                }
            }
        }
    }
}

extern "C" void kernel_launch(void* const* d_in, const int* in_sizes, int n_in,
                              void* d_out, int out_size, void* d_ws, size_t ws_size,
                              hipStream_t stream) {
    const float* x  = (const float*)d_in[0];
    const float* wb = (const float*)d_in[1];
    const float* a1 = (const float*)d_in[2];
    const float* wd = (const float*)d_in[3];
    const float* a2 = (const float*)d_in[4];
    const float* wr = (const float*)d_in[5];
    const float* wk = (const float*)d_in[6];
    float* out = (float*)d_out;

    short* wbt = (short*)d_ws;            // 65536 bf16
    short* wct = wbt + 65536;             // 131072 bf16

    prep_weights<<<dim3(768), dim3(256), 0, stream>>>(wb, wr, wk, wbt, wct);
    conv1d_block_mfma<<<dim3(NB * (NT / TB)), dim3(256), 0, stream>>>(
        x, a1, wd, a2, wbt, wct, out);
}